// Round 1
// baseline (332.801 us; speedup 1.0000x reference)
//
#include <hip/hip_runtime.h>
#include <cstdint>

// YOLO head decode: [B, 3*86, 76, 76] fp32 -> [B, 3*76*76, 86] fp32
// Per (b,a): transpose [86 ch x 5776 sp] -> [5776 sp x 86 ch] with activations.
//   c==0: (sigmoid(v) + i) * 8
//   c==1: (sigmoid(v) + j) * 8
//   c==2: exp(v) * anchor_w[a]   (anchor/stride * stride cancels)
//   c==3: exp(v) * anchor_h[a]
//   c>=4: sigmoid(v)

#define GDIM 76
#define SP   (GDIM * GDIM)   // 5776
#define NCH  86
#define NANC 3
#define TS   64              // spatial positions per tile

__global__ __launch_bounds__(256) void yolo_decode_kernel(
    const float* __restrict__ in, float* __restrict__ out) {
    // padded tile: stride 65 -> LDS bank stride 1 on the transposed read
    __shared__ float tile[NCH][TS + 1];   // 86*65*4 = 22360 B

    const int tid   = threadIdx.x;
    const int chunk = blockIdx.x;        // 0..90
    const int a     = blockIdx.y;        // 0..2
    const int b     = blockIdx.z;        // 0..B-1
    const int s0    = chunk * TS;
    const int valid = min(TS, SP - s0);  // 64, or 16 in the tail chunk (mult of 4)

    const float* inp = in + ((size_t)(b * (NANC * NCH) + a * NCH)) * SP + s0;

    // ---- load phase: 86 rows x 16 float4 = 1376 vec4 loads, coalesced ----
    const int nvec4 = NCH * (TS / 4);    // 1376
    for (int idx = tid; idx < nvec4; idx += 256) {
        const int c  = idx >> 4;
        const int s4 = (idx & 15) << 2;
        if (s4 < valid) {                // valid is always a multiple of 4
            const float4 v = *(const float4*)(inp + (size_t)c * SP + s4);
            tile[c][s4 + 0] = v.x;
            tile[c][s4 + 1] = v.y;
            tile[c][s4 + 2] = v.z;
            tile[c][s4 + 3] = v.w;
        }
    }
    __syncthreads();

    // ---- compute + store phase: [valid sp x 86 ch] contiguous out ----
    const float aw_tab[NANC] = {116.0f, 156.0f, 373.0f};
    const float ah_tab[NANC] = { 90.0f, 198.0f, 326.0f};
    const float aw = aw_tab[a];
    const float ah = ah_tab[a];

    float* outp = out + ((size_t)b * (NANC * SP) + (size_t)a * SP + s0) * NCH;

    for (int idx = tid; idx < TS * NCH; idx += 256) {
        const int s = idx / NCH;          // magic-mul division
        const int c = idx - s * NCH;
        if (s < valid) {
            const int   sp  = s0 + s;
            const float v   = tile[c][s];
            const float sig = 1.0f / (1.0f + __expf(-v));
            float r = sig;
            if (c < 4) {
                if (c == 0)      r = (sig + (float)(sp % GDIM)) * 8.0f;
                else if (c == 1) r = (sig + (float)(sp / GDIM)) * 8.0f;
                else if (c == 2) r = __expf(v) * aw;
                else             r = __expf(v) * ah;
            }
            outp[(size_t)s * NCH + c] = r;
        }
    }
}

extern "C" void kernel_launch(void* const* d_in, const int* in_sizes, int n_in,
                              void* d_out, int out_size, void* d_ws, size_t ws_size,
                              hipStream_t stream) {
    const float* in = (const float*)d_in[0];
    float* out = (float*)d_out;
    const int B = in_sizes[0] / (NANC * NCH * SP);   // 32
    dim3 grid((SP + TS - 1) / TS, NANC, B);          // (91, 3, 32)
    yolo_decode_kernel<<<grid, 256, 0, stream>>>(in, out);
}

// Round 3
// 323.192 us; speedup vs baseline: 1.0297x; 1.0297x over previous
//
#include <hip/hip_runtime.h>
#include <cstdint>

// YOLO head decode: [B, 3*86, 76, 76] fp32 -> [B, 3*76*76, 86] fp32
// c0: (sig(v)+i)*8, c1: (sig(v)+j)*8, c2: exp(v)*aw, c3: exp(v)*ah, c>=4: sig(v)
// (anchor/stride * stride cancels -> raw anchors)

#define GDIM 76
#define SP   (GDIM * GDIM)   // 5776
#define NCH  86
#define NANC 3
#define TS   64              // spatial positions per tile
#define NV   (NCH * TS / 4)  // 1376 float4 per full tile

typedef float v4f __attribute__((ext_vector_type(4)));

__global__ __launch_bounds__(256) void yolo_decode_kernel(
    const float* __restrict__ in, float* __restrict__ out) {
    __shared__ float tile[NCH][TS + 1];   // stride 65: c-consecutive -> bank-consecutive

    const int tid   = threadIdx.x;
    const int chunk = blockIdx.x;        // 0..90
    const int a     = blockIdx.y;        // 0..2
    const int b     = blockIdx.z;        // 0..B-1
    const int s0    = chunk * TS;
    const int valid = min(TS, SP - s0);  // 64, or 16 tail (mult of 4)

    const float* inp = in + ((size_t)(b * (NANC * NCH) + a * NCH)) * SP + s0;

    // ---- load: 86 rows x 16 float4, coalesced ----
    #pragma unroll
    for (int k = 0; k < 6; ++k) {
        const int idx = tid + (k << 8);
        if (idx < NV) {
            const int c  = idx >> 4;
            const int s4 = (idx & 15) << 2;
            if (s4 < valid) {
                const v4f v = *(const v4f*)(inp + (size_t)c * SP + s4);
                tile[c][s4 + 0] = v.x;
                tile[c][s4 + 1] = v.y;
                tile[c][s4 + 2] = v.z;
                tile[c][s4 + 3] = v.w;
            }
        }
    }
    __syncthreads();

    // ---- compute + vectorized store ----
    const float aw = (a == 0) ? 116.0f : (a == 1) ? 156.0f : 373.0f;
    const float ah = (a == 0) ?  90.0f : (a == 1) ? 198.0f : 326.0f;

    // block's output region is contiguous: valid*86 floats, 16B-aligned
    v4f* outp = (v4f*)(out + ((size_t)b * (NANC * SP) + (size_t)a * SP + (size_t)s0) * NCH);
    const int nvalid = (valid * NCH) >> 2;   // 1376 or 344

    #pragma unroll
    for (int k = 0; k < 6; ++k) {
        const int v = tid + (k << 8);
        if (v < nvalid) {
            const int e0 = v << 2;
            const int s  = e0 / NCH;          // magic-mul
            const int c0 = e0 - s * NCH;      // even, 0..84

            // gather 4 values (c-consecutive, wraps to next s at c==86)
            float vals[4];
            {
                int c = c0, ss = s;
                #pragma unroll
                for (int j = 0; j < 4; ++j) {
                    vals[j] = tile[c][ss];
                    ++c; if (c == NCH) { c = 0; ++ss; }
                }
            }

            v4f rr;
            {
                int c = c0, ss = s;
                #pragma unroll
                for (int j = 0; j < 4; ++j) {
                    const float x  = vals[j];
                    const float en = __expf(-x);                         // exp(-x)
                    const float sg = __builtin_amdgcn_rcpf(1.0f + en);   // sigmoid
                    float r = sg;
                    if (c < 4) {
                        const int sp_ = s0 + ss;
                        if      (c == 0) r = (sg + (float)(sp_ % GDIM)) * 8.0f;
                        else if (c == 1) r = (sg + (float)(sp_ / GDIM)) * 8.0f;
                        else if (c == 2) r = __builtin_amdgcn_rcpf(en) * aw;  // exp(x)*aw
                        else             r = __builtin_amdgcn_rcpf(en) * ah;
                    }
                    rr[j] = r;
                    ++c; if (c == NCH) { c = 0; ++ss; }
                }
            }
            __builtin_nontemporal_store(rr, outp + v);
        }
    }
}

extern "C" void kernel_launch(void* const* d_in, const int* in_sizes, int n_in,
                              void* d_out, int out_size, void* d_ws, size_t ws_size,
                              hipStream_t stream) {
    const float* in = (const float*)d_in[0];
    float* out = (float*)d_out;
    const int B = in_sizes[0] / (NANC * NCH * SP);   // 32
    dim3 grid((SP + TS - 1) / TS, NANC, B);          // (91, 3, 32)
    yolo_decode_kernel<<<grid, 256, 0, stream>>>(in, out);
}